// Round 3
// baseline (162.798 us; speedup 1.0000x reference)
//
#include <hip/hip_runtime.h>
#include <math.h>

#pragma clang fp contract(off)

#define Bn 2
#define Vn 8000
#define Fn 1500
#define Hn 128
#define Wn 128
#define EPS_AREA_F 1e-8f
#define EPS_Z_F 1e-4f
#define NSEG 16
#define NSORT 2048

struct FaceRec {
    float x0, y0, x1, y1, x2, y2, area, as, z0, z1, z2, lb;
};

__device__ inline FaceRec project_face(const float* __restrict__ verts,
                                       const float* __restrict__ R,
                                       const float* __restrict__ T,
                                       float fo, const int* __restrict__ faces,
                                       int b, int f) {
    const float* Rb = R + b * 9;
    const float* Tb = T + b * 3;
    float X[3], Y[3], Z[3];
    for (int k = 0; k < 3; ++k) {
        int vi = faces[f * 3 + k];
        const float* v = verts + ((size_t)b * Vn + vi) * 3;
        float v0 = v[0], v1 = v[1], v2 = v[2];
        float vx = v0 * Rb[0] + v1 * Rb[3] + v2 * Rb[6] + Tb[0];
        float vy = v0 * Rb[1] + v1 * Rb[4] + v2 * Rb[7] + Tb[1];
        float vz = v0 * Rb[2] + v1 * Rb[5] + v2 * Rb[8] + Tb[2];
        X[k] = (fo * vx) / vz;
        Y[k] = (fo * vy) / vz;
        Z[k] = vz;
    }
    FaceRec r;
    r.x0 = X[0]; r.y0 = Y[0]; r.x1 = X[1]; r.y1 = Y[1]; r.x2 = X[2]; r.y2 = Y[2];
    r.z0 = Z[0]; r.z1 = Z[1]; r.z2 = Z[2];
    r.area = (X[2] - X[0]) * (Y[1] - Y[0]) - (Y[2] - Y[0]) * (X[1] - X[0]);
    r.as = (fabsf(r.area) > EPS_AREA_F) ? r.area : EPS_AREA_F;
    // Conservative lower bound on any computed zp for an "inside" pixel of this
    // face: zp >= minz - error.  w-error ~ ulp * max coord^2; b-error = w-err/|as|;
    // zp-err ~ 3*b_err*max|z|.  Generous constants (8x, 4x) make the bound safe.
    float minz = fminf(Z[0], fminf(Z[1], Z[2]));
    float A = fmaxf(fabsf(Z[0]), fmaxf(fabsf(Z[1]), fabsf(Z[2])));
    float M = fmaxf(1.0f,
              fmaxf(fmaxf(fabsf(X[0]), fabsf(Y[0])),
              fmaxf(fmaxf(fabsf(X[1]), fabsf(Y[1])),
                    fmaxf(fabsf(X[2]), fabsf(Y[2])))));
    float Ew = 8.0f * 5.96e-8f * M * M;
    float Eb = Ew / fabsf(r.as);
    float Ez = 3.0f * Eb * A + 1e-5f * A + 1e-6f;
    float lb = minz - 4.0f * Ez;
    if (fabsf(r.area) <= EPS_AREA_F) lb = -3.0e38f;   // clamped-area: no bound holds
    if (!(lb >= -3.0e38f && lb <= 3.0e38f)) lb = -3.0e38f;  // NaN/inf guard
    r.lb = lb;
    return r;
}

// One block per batch: project all faces, bitonic-sort by quantized lb, write
// sorted records.  r2.w packs (lb_q16 << 16) | origIdx; lb_q16 is lb rounded
// DOWN (toward -inf) to 16 bits, so the stored bound stays conservative.
__global__ __launch_bounds__(1024)
void prep_sort_kernel(const float* __restrict__ verts, const float* __restrict__ R,
                      const float* __restrict__ T, const float* __restrict__ focal,
                      const int* __restrict__ faces, float4* __restrict__ recS) {
    __shared__ unsigned long long sk[NSORT];
    int b = blockIdx.x, tid = threadIdx.x;
    float fo = focal[0];
    for (int f = tid; f < NSORT; f += 1024) {
        unsigned long long e = ~0ull;
        if (f < Fn) {
            FaceRec r = project_face(verts, R, T, fo, faces, b, f);
            unsigned ub = __float_as_uint(r.lb);
            if (r.lb < 0.0f) ub += 0xFFFFu;      // round magnitude up (toward -inf)
            ub &= 0xFFFF0000u;
            unsigned k = (ub & 0x80000000u) ? ~ub : (ub ^ 0x80000000u);  // sortable
            e = ((unsigned long long)k << 32) | (unsigned)f;
        }
        sk[f] = e;
    }
    __syncthreads();
    for (int k = 2; k <= NSORT; k <<= 1)
        for (int j = k >> 1; j > 0; j >>= 1) {
            for (int i = tid; i < NSORT; i += 1024) {
                int ixj = i ^ j;
                if (ixj > i) {
                    unsigned long long a = sk[i], c = sk[ixj];
                    bool sw = ((i & k) == 0) ? (a > c) : (a < c);
                    if (sw) { sk[i] = c; sk[ixj] = a; }
                }
            }
            __syncthreads();
        }
    for (int rank = tid; rank < Fn; rank += 1024) {
        unsigned long long e = sk[rank];
        int f = (int)(e & 0xFFFFFFFFu);
        unsigned ku = (unsigned)(e >> 32);
        unsigned ub = (ku & 0x80000000u) ? (ku ^ 0x80000000u) : ~ku;  // inverse
        FaceRec r = project_face(verts, R, T, fo, faces, b, f);
        size_t o = ((size_t)b * Fn + rank) * 3;
        recS[o + 0] = make_float4(r.x0, r.y0, r.x1, r.y1);
        recS[o + 1] = make_float4(r.x2, r.y2, r.area, r.as);
        recS[o + 2] = make_float4(r.z0, r.z1, r.z2,
                                  __uint_as_float(ub | (unsigned)f));
    }
}

__global__ __launch_bounds__(1024)
void raster_kernel(const float4* __restrict__ recS, float* __restrict__ out) {
    __shared__ unsigned long long smK[NSEG * 64];   // 8 KB

    int tid = threadIdx.x;
    int lane = tid & 63;
    int seg = tid >> 6;
    int blk = blockIdx.x;
    int b = blk >> 8;
    int tile = blk & 255;
    int h = ((tile >> 4) << 3) | (lane >> 3);   // 8x8 pixel tile per block
    int w = ((tile & 15) << 3) | (lane & 7);
    float px = 1.0f - (2.0f * ((float)w + 0.5f)) / (float)Wn;
    float py = 1.0f - (2.0f * ((float)h + 0.5f)) / (float)Hn;

    const float4* rb = recS + (size_t)b * Fn * 3;

    float zmin = __builtin_inff();
    unsigned long long best = ~0ull;

    for (int r = seg; r < Fn; r += NSEG) {
        const float4* pr = rb + (size_t)r * 3;
        float4 q2 = pr[2];
        unsigned ub = __float_as_uint(q2.w);
        float lb = __uint_as_float(ub & 0xFFFF0000u);
        bool want = (lb <= zmin);          // lb monotone in r => once false, stays false
        if (__ballot(want) == 0) break;    // wave-uniform exit
        if (want) {
            float4 q0 = pr[0];
            float4 q1 = pr[1];
            float x0 = q0.x, y0 = q0.y, x1 = q0.z, y1 = q0.w;
            float x2 = q1.x, y2 = q1.y, area = q1.z, as = q1.w;
            // exact reference op order (_edge), contraction off
            float w0 = (px - x1) * (y2 - y1) - (py - y1) * (x2 - x1);
            float w1 = (px - x2) * (y0 - y2) - (py - y2) * (x0 - x2);
            float w2 = (px - x0) * (y1 - y0) - (py - y0) * (x1 - x0);
            bool areaok = fabsf(area) > EPS_AREA_F;
            bool ins = areaok && ((as > 0.0f)
                       ? (w0 >= 0.0f && w1 >= 0.0f && w2 >= 0.0f)
                       : (w0 <= 0.0f && w1 <= 0.0f && w2 <= 0.0f));
            if (ins) {
                float b0 = w0 / as;
                float b1 = w1 / as;
                float b2 = w2 / as;
                float zp = (b0 * q2.x + b1 * q2.y) + b2 * q2.z;
                if (zp > EPS_Z_F) {
                    // key: z (primary), origIdx (argmin-first tie-break), rank
                    unsigned long long ck =
                        ((unsigned long long)__float_as_uint(zp) << 32) |
                        ((unsigned long long)(ub & 0xFFFFu) << 16) | (unsigned)r;
                    if (ck < best) { best = ck; zmin = zp; }
                }
            }
        }
    }
    smK[seg * 64 + lane] = best;
    __syncthreads();

    if (tid < 64) {
        unsigned long long bk = smK[tid];
        #pragma unroll
        for (int s = 1; s < NSEG; ++s) {
            unsigned long long k = smK[s * 64 + tid];
            if (k < bk) bk = k;
        }
        const int HWB = Bn * Hn * Wn;
        int p = b * (Hn * Wn) + h * Wn + w;
        float o_idx = -1.0f, o_z = -1.0f, ob0 = -1.0f, ob1 = -1.0f, ob2 = -1.0f, o_d = -1.0f;
        if (bk != ~0ull) {
            int rank = (int)(bk & 0xFFFFu);
            int fidx = (int)((bk >> 16) & 0xFFFFu);
            float4 q0 = rb[(size_t)rank * 3 + 0];
            float4 q1 = rb[(size_t)rank * 3 + 1];
            float x0 = q0.x, y0 = q0.y, x1 = q0.z, y1 = q0.w;
            float x2 = q1.x, y2 = q1.y, as = q1.w;
            // winner bary, exactly the reference phase-2 expressions
            float w0 = (px - x1) * (y2 - y1) - (py - y1) * (x2 - x1);
            float w1 = (px - x2) * (y0 - y2) - (py - y2) * (x0 - x2);
            float w2 = (px - x0) * (y1 - y0) - (py - y0) * (x1 - x0);
            float c0 = w0 / as, c1 = w1 / as, c2 = w2 / as;
            auto segd = [&](float ax, float ay, float bx, float by) -> float {
                float dx = bx - ax, dy = by - ay;
                float l2 = dx * dx + dy * dy;
                l2 = (l2 > 1e-12f) ? l2 : 1e-12f;
                float q = ((px - ax) * dx + (py - ay) * dy) / l2;
                q = (q < 0.0f) ? 0.0f : ((q > 1.0f) ? 1.0f : q);
                float ex = (ax + q * dx) - px;
                float ey = (ay + q * dy) - py;
                return ex * ex + ey * ey;
            };
            float d2 = fminf(fminf(segd(x0, y0, x1, y1), segd(x1, y1, x2, y2)),
                             segd(x2, y2, x0, y0));
            bool inside_b = (c0 >= 0.0f) && (c1 >= 0.0f) && (c2 >= 0.0f);
            o_idx = (float)fidx;
            o_z = __uint_as_float((unsigned)(bk >> 32));
            ob0 = c0; ob1 = c1; ob2 = c2;
            o_d = inside_b ? -d2 : d2;
        }
        out[p] = o_idx;
        out[HWB + p] = o_z;
        out[2 * HWB + p * 3 + 0] = ob0;
        out[2 * HWB + p * 3 + 1] = ob1;
        out[2 * HWB + p * 3 + 2] = ob2;
        out[5 * HWB + p] = o_d;
    }
}

extern "C" void kernel_launch(void* const* d_in, const int* in_sizes, int n_in,
                              void* d_out, int out_size, void* d_ws, size_t ws_size,
                              hipStream_t stream) {
    const float* verts = (const float*)d_in[0];
    const float* R     = (const float*)d_in[1];
    const float* T     = (const float*)d_in[2];
    const float* focal = (const float*)d_in[3];
    const int*   faces = (const int*)d_in[4];
    float* out = (float*)d_out;
    float4* recS = (float4*)d_ws;   // B*F*3 float4 = 144000 B (same as proven R2 usage)

    hipLaunchKernelGGL(prep_sort_kernel, dim3(Bn), dim3(1024), 0, stream,
                       verts, R, T, focal, faces, recS);
    hipLaunchKernelGGL(raster_kernel, dim3(Bn * 256), dim3(1024), 0, stream,
                       recS, out);
}

// Round 4
// 153.232 us; speedup vs baseline: 1.0624x; 1.0624x over previous
//
#include <hip/hip_runtime.h>
#include <math.h>

#pragma clang fp contract(off)

#define Bn 2
#define Vn 8000
#define Fn 1500
#define Hn 128
#define Wn 128
#define EPS_AREA_F 1e-8f
#define EPS_Z_F 1e-4f
#define NWORD 24            // ceil(1500/64) bitmask words per tile
#define NSEG 8              // waves per tile-block
#define TPB (NSEG * 64)

// recS: per face 3 x float4 = {x0,y0,x1,y1}, {x2,y2,area,as}, {z0,z1,z2,0}
// bins: [Bn][256 tiles][NWORD] u64 bitmask of face indices

__global__ void zero_kernel(unsigned long long* __restrict__ bins) {
    int i = blockIdx.x * blockDim.x + threadIdx.x;
    if (i < Bn * 256 * NWORD) bins[i] = 0ull;
}

__global__ void prep_kernel(const float* __restrict__ verts, const float* __restrict__ R,
                            const float* __restrict__ T, const float* __restrict__ focal,
                            const int* __restrict__ faces,
                            float4* __restrict__ recS, unsigned long long* __restrict__ bins) {
    int t = blockIdx.x * blockDim.x + threadIdx.x;
    if (t >= Bn * Fn) return;
    int b = t / Fn;
    int f = t - b * Fn;
    const float* Rb = R + b * 9;
    const float* Tb = T + b * 3;
    float fo = focal[0];
    float X[3], Y[3], Z[3];
    for (int k = 0; k < 3; ++k) {
        int vi = faces[f * 3 + k];
        const float* v = verts + ((size_t)b * Vn + vi) * 3;
        float v0 = v[0], v1 = v[1], v2 = v[2];
        float vx = v0 * Rb[0] + v1 * Rb[3] + v2 * Rb[6] + Tb[0];
        float vy = v0 * Rb[1] + v1 * Rb[4] + v2 * Rb[7] + Tb[1];
        float vz = v0 * Rb[2] + v1 * Rb[5] + v2 * Rb[8] + Tb[2];
        X[k] = (fo * vx) / vz;
        Y[k] = (fo * vy) / vz;
        Z[k] = vz;
    }
    float area = (X[2] - X[0]) * (Y[1] - Y[0]) - (Y[2] - Y[0]) * (X[1] - X[0]);
    float as = (fabsf(area) > EPS_AREA_F) ? area : EPS_AREA_F;
    recS[t * 3 + 0] = make_float4(X[0], Y[0], X[1], Y[1]);
    recS[t * 3 + 1] = make_float4(X[2], Y[2], area, as);
    recS[t * 3 + 2] = make_float4(Z[0], Z[1], Z[2], 0.0f);

    // Degenerate/NaN area => reference 'inside' is false for every pixel: exact skip.
    if (!(fabsf(area) > EPS_AREA_F)) return;

    float xmin = fminf(X[0], fminf(X[1], X[2]));
    float xmax = fmaxf(X[0], fmaxf(X[1], X[2]));
    float ymin = fminf(Y[0], fminf(Y[1], Y[2]));
    float ymax = fmaxf(Y[0], fmaxf(Y[1], Y[2]));
    // px(w) = 1 - (w+0.5)/64, decreasing in w.  D = 0.02 NDC (~1.3 px) pad —
    // fp sign-flip dilation is <1e-5 NDC, so this is very conservative.
    const float D = 0.02f;
    float wlo = ceilf(64.0f * (1.0f - xmax - D) - 0.5f);
    float whi = floorf(64.0f * (1.0f - xmin + D) - 0.5f);
    float hlo = ceilf(64.0f * (1.0f - ymax - D) - 0.5f);
    float hhi = floorf(64.0f * (1.0f - ymin + D) - 0.5f);
    wlo = fmaxf(wlo, 0.0f); whi = fminf(whi, 127.0f);
    hlo = fmaxf(hlo, 0.0f); hhi = fminf(hhi, 127.0f);
    // NaN-safe: any NaN coord makes a comparison false -> skip (NaN face can't hit);
    // +-inf coords clamp to full screen (conservative).
    if (!(wlo <= whi) || !(hlo <= hhi)) return;
    int tx0 = (int)wlo >> 3, tx1 = (int)whi >> 3;
    int ty0 = (int)hlo >> 3, ty1 = (int)hhi >> 3;
    unsigned long long* bb = bins + (size_t)b * 256 * NWORD + (f >> 6);
    unsigned long long mask = 1ull << (f & 63);
    for (int ty = ty0; ty <= ty1; ++ty)
        for (int tx = tx0; tx <= tx1; ++tx)
            atomicOr(bb + (ty * 16 + tx) * NWORD, mask);
}

__global__ __launch_bounds__(TPB)
void raster_kernel(const float4* __restrict__ recS,
                   const unsigned long long* __restrict__ bins,
                   float* __restrict__ out) {
    __shared__ unsigned long long smK[NSEG * 64];   // 4 KB

    int tid = threadIdx.x;
    int lane = tid & 63;
    int seg = tid >> 6;
    int blk = blockIdx.x;
    int b = blk >> 8;
    int tile = blk & 255;
    int h = ((tile >> 4) << 3) | (lane >> 3);   // 8x8 pixel tile per block
    int w = ((tile & 15) << 3) | (lane & 7);
    float px = 1.0f - (2.0f * ((float)w + 0.5f)) / (float)Wn;
    float py = 1.0f - (2.0f * ((float)h + 0.5f)) / (float)Hn;

    const float4* rb = recS + (size_t)b * Fn * 3;
    const unsigned long long* bt = bins + ((size_t)b * 256 + tile) * NWORD;

    unsigned long long best = ~0ull;

    for (int wd = seg; wd < NWORD; wd += NSEG) {      // 3 words per wave
        unsigned long long m = bt[wd];
        while (m) {
            int bit = __ffsll((unsigned long long)m) - 1;
            m &= m - 1;
            int f = (wd << 6) + bit;
            const float4* pr = rb + (size_t)f * 3;
            float4 q0 = pr[0];
            float4 q1 = pr[1];
            float x0 = q0.x, y0 = q0.y, x1 = q0.z, y1 = q0.w;
            float x2 = q1.x, y2 = q1.y, area = q1.z, as = q1.w;
            // exact reference op order (_edge), contraction off
            float w0 = (px - x1) * (y2 - y1) - (py - y1) * (x2 - x1);
            float w1 = (px - x2) * (y0 - y2) - (py - y2) * (x0 - x2);
            float w2 = (px - x0) * (y1 - y0) - (py - y0) * (x1 - x0);
            bool ins = (as > 0.0f) ? (w0 >= 0.0f && w1 >= 0.0f && w2 >= 0.0f)
                                   : (w0 <= 0.0f && w1 <= 0.0f && w2 <= 0.0f);
            // (binned faces all have |area| > EPS_AREA, so areaok is implied)
            if (ins) {
                float b0 = w0 / as;
                float b1 = w1 / as;
                float b2 = w2 / as;
                float4 q2 = pr[2];
                float zp = (b0 * q2.x + b1 * q2.y) + b2 * q2.z;
                if (zp > EPS_Z_F) {
                    unsigned long long ck =
                        ((unsigned long long)__float_as_uint(zp) << 32) | (unsigned)f;
                    if (ck < best) best = ck;   // min z, then min face idx = argmin-first
                }
            }
        }
    }
    smK[seg * 64 + lane] = best;
    __syncthreads();

    if (tid < 64) {
        unsigned long long bk = smK[tid];
        #pragma unroll
        for (int s = 1; s < NSEG; ++s) {
            unsigned long long k = smK[s * 64 + tid];
            if (k < bk) bk = k;
        }
        const int HWB = Bn * Hn * Wn;
        int p = b * (Hn * Wn) + h * Wn + w;
        float o_idx = -1.0f, o_z = -1.0f, ob0 = -1.0f, ob1 = -1.0f, ob2 = -1.0f, o_d = -1.0f;
        if (bk != ~0ull) {
            int f = (int)(bk & 0xFFFFFFFFu);
            float4 q0 = rb[(size_t)f * 3 + 0];
            float4 q1 = rb[(size_t)f * 3 + 1];
            float x0 = q0.x, y0 = q0.y, x1 = q0.z, y1 = q0.w;
            float x2 = q1.x, y2 = q1.y, as = q1.w;
            // winner bary: exactly the reference phase-2 expressions
            float w0 = (px - x1) * (y2 - y1) - (py - y1) * (x2 - x1);
            float w1 = (px - x2) * (y0 - y2) - (py - y2) * (x0 - x2);
            float w2 = (px - x0) * (y1 - y0) - (py - y0) * (x1 - x0);
            float c0 = w0 / as, c1 = w1 / as, c2 = w2 / as;
            auto segd = [&](float ax, float ay, float bx, float by) -> float {
                float dx = bx - ax, dy = by - ay;
                float l2 = dx * dx + dy * dy;
                l2 = (l2 > 1e-12f) ? l2 : 1e-12f;
                float q = ((px - ax) * dx + (py - ay) * dy) / l2;
                q = (q < 0.0f) ? 0.0f : ((q > 1.0f) ? 1.0f : q);
                float ex = (ax + q * dx) - px;
                float ey = (ay + q * dy) - py;
                return ex * ex + ey * ey;
            };
            float d2 = fminf(fminf(segd(x0, y0, x1, y1), segd(x1, y1, x2, y2)),
                             segd(x2, y2, x0, y0));
            bool inside_b = (c0 >= 0.0f) && (c1 >= 0.0f) && (c2 >= 0.0f);
            o_idx = (float)f;
            o_z = __uint_as_float((unsigned)(bk >> 32));
            ob0 = c0; ob1 = c1; ob2 = c2;
            o_d = inside_b ? -d2 : d2;
        }
        out[p] = o_idx;
        out[HWB + p] = o_z;
        out[2 * HWB + p * 3 + 0] = ob0;
        out[2 * HWB + p * 3 + 1] = ob1;
        out[2 * HWB + p * 3 + 2] = ob2;
        out[5 * HWB + p] = o_d;
    }
}

extern "C" void kernel_launch(void* const* d_in, const int* in_sizes, int n_in,
                              void* d_out, int out_size, void* d_ws, size_t ws_size,
                              hipStream_t stream) {
    const float* verts = (const float*)d_in[0];
    const float* R     = (const float*)d_in[1];
    const float* T     = (const float*)d_in[2];
    const float* focal = (const float*)d_in[3];
    const int*   faces = (const int*)d_in[4];
    float* out = (float*)d_out;
    float4* recS = (float4*)d_ws;                            // 144000 B
    unsigned long long* bins =
        (unsigned long long*)((char*)d_ws + (size_t)Bn * Fn * 3 * sizeof(float4));
                                                             // + 98304 B = 242 KB total

    hipLaunchKernelGGL(zero_kernel, dim3((Bn * 256 * NWORD + 255) / 256), dim3(256),
                       0, stream, bins);
    hipLaunchKernelGGL(prep_kernel, dim3((Bn * Fn + 255) / 256), dim3(256), 0, stream,
                       verts, R, T, focal, faces, recS, bins);
    hipLaunchKernelGGL(raster_kernel, dim3(Bn * 256), dim3(TPB), 0, stream,
                       recS, bins, out);
}

// Round 5
// 102.755 us; speedup vs baseline: 1.5843x; 1.4912x over previous
//
#include <hip/hip_runtime.h>
#include <math.h>

#pragma clang fp contract(off)

#define Bn 2
#define Vn 8000
#define Fn 1500
#define Hn 128
#define Wn 128
#define EPS_AREA_F 1e-8f
#define EPS_Z_F 1e-4f
#define NWORD 24            // ceil(1500/64) bitmask words per tile
#define NSEG 8              // waves per raster block
#define NSLICE 8            // raster blocks per tile
#define TPB (NSEG * 64)
#define MAXL 1536

// ws layout (517 KB):
//   recS  : float4[Bn*Fn*3]      @ 0        (144000 B)
//   bboxT : u32[Bn*Fn]           @ 144000   (12000 B)
//   bins  : u64[Bn*256*NWORD]    @ 156000   (98304 B)
//   keybuf: u64[Bn*16384]        @ 254304   (262144 B)

__global__ void zero_kernel(unsigned long long* __restrict__ bins,
                            unsigned long long* __restrict__ keybuf) {
    int i = blockIdx.x * blockDim.x + threadIdx.x;
    int n1 = Bn * 256 * NWORD;
    int n2 = Bn * Hn * Wn;
    if (i < n1) bins[i] = 0ull;
    else if (i < n1 + n2) keybuf[i - n1] = ~0ull;
}

__global__ void proj_kernel(const float* __restrict__ verts, const float* __restrict__ R,
                            const float* __restrict__ T, const float* __restrict__ focal,
                            const int* __restrict__ faces,
                            float4* __restrict__ recS, unsigned* __restrict__ bboxT) {
    int t = blockIdx.x * blockDim.x + threadIdx.x;
    if (t >= Bn * Fn) return;
    int b = t / Fn;
    int f = t - b * Fn;
    const float* Rb = R + b * 9;
    const float* Tb = T + b * 3;
    float fo = focal[0];
    float X[3], Y[3], Z[3];
    for (int k = 0; k < 3; ++k) {
        int vi = faces[f * 3 + k];
        const float* v = verts + ((size_t)b * Vn + vi) * 3;
        float v0 = v[0], v1 = v[1], v2 = v[2];
        float vx = v0 * Rb[0] + v1 * Rb[3] + v2 * Rb[6] + Tb[0];
        float vy = v0 * Rb[1] + v1 * Rb[4] + v2 * Rb[7] + Tb[1];
        float vz = v0 * Rb[2] + v1 * Rb[5] + v2 * Rb[8] + Tb[2];
        X[k] = (fo * vx) / vz;
        Y[k] = (fo * vy) / vz;
        Z[k] = vz;
    }
    float area = (X[2] - X[0]) * (Y[1] - Y[0]) - (Y[2] - Y[0]) * (X[1] - X[0]);
    float as = (fabsf(area) > EPS_AREA_F) ? area : EPS_AREA_F;
    recS[t * 3 + 0] = make_float4(X[0], Y[0], X[1], Y[1]);
    recS[t * 3 + 1] = make_float4(X[2], Y[2], area, as);
    recS[t * 3 + 2] = make_float4(Z[0], Z[1], Z[2], 0.0f);

    unsigned pk = 0xFFFFFFFFu;   // sentinel: skip face
    // Degenerate/NaN area => reference 'inside' false everywhere: exact skip.
    if (fabsf(area) > EPS_AREA_F) {
        float xmin = fminf(X[0], fminf(X[1], X[2]));
        float xmax = fmaxf(X[0], fmaxf(X[1], X[2]));
        float ymin = fminf(Y[0], fminf(Y[1], Y[2]));
        float ymax = fmaxf(Y[0], fmaxf(Y[1], Y[2]));
        const float D = 0.02f;   // pad >> max fp sign-flip dilation (~1e-5 NDC)
        float wlo = ceilf(64.0f * (1.0f - xmax - D) - 0.5f);
        float whi = floorf(64.0f * (1.0f - xmin + D) - 0.5f);
        float hlo = ceilf(64.0f * (1.0f - ymax - D) - 0.5f);
        float hhi = floorf(64.0f * (1.0f - ymin + D) - 0.5f);
        wlo = fmaxf(wlo, 0.0f); whi = fminf(whi, 127.0f);
        hlo = fmaxf(hlo, 0.0f); hhi = fminf(hhi, 127.0f);
        // NaN-safe: NaN comparisons fail -> skip; +-inf clamps to full screen.
        if ((wlo <= whi) && (hlo <= hhi)) {
            int tx0 = (int)wlo >> 3, tx1 = (int)whi >> 3;
            int ty0 = (int)hlo >> 3, ty1 = (int)hhi >> 3;
            pk = (unsigned)tx0 | ((unsigned)tx1 << 8) |
                 ((unsigned)ty0 << 16) | ((unsigned)ty1 << 24);
        }
    }
    bboxT[t] = pk;
}

// thread per (face, tile-row): high parallelism, <=16 atomics per thread
__global__ void bin_kernel(const unsigned* __restrict__ bboxT,
                           unsigned long long* __restrict__ bins) {
    int t = blockIdx.x * blockDim.x + threadIdx.x;
    if (t >= Bn * Fn * 16) return;
    int ty = t & 15;
    int bf = t >> 4;
    int b = bf / Fn;
    int f = bf - b * Fn;
    unsigned pk = bboxT[bf];
    if (pk == 0xFFFFFFFFu) return;
    int tx0 = pk & 0xFF, tx1 = (pk >> 8) & 0xFF;
    int ty0 = (pk >> 16) & 0xFF, ty1 = (pk >> 24) & 0xFF;
    if (ty < ty0 || ty > ty1) return;
    unsigned long long* bb = bins + ((size_t)b * 256 + ty * 16) * NWORD + (f >> 6);
    unsigned long long m = 1ull << (f & 63);
    for (int tx = tx0; tx <= tx1; ++tx)
        atomicOr(bb + (size_t)tx * NWORD, m);
}

__global__ __launch_bounds__(TPB)
void raster_kernel(const float4* __restrict__ recS,
                   const unsigned long long* __restrict__ bins,
                   unsigned long long* __restrict__ keybuf) {
    __shared__ unsigned short smList[MAXL];
    __shared__ int smCnt[NWORD];
    __shared__ int smL;
    __shared__ unsigned long long smK[NSEG * 64];

    int tid = threadIdx.x;
    int lane = tid & 63;
    int seg = tid >> 6;
    int blk = blockIdx.x;
    int slice = blk & (NSLICE - 1);
    int bt_ = blk >> 3;           // /NSLICE
    int b = bt_ >> 8;
    int tile = bt_ & 255;
    int h = ((tile >> 4) << 3) | (lane >> 3);
    int w = ((tile & 15) << 3) | (lane & 7);
    float px = 1.0f - (2.0f * ((float)w + 0.5f)) / (float)Wn;
    float py = 1.0f - (2.0f * ((float)h + 0.5f)) / (float)Hn;

    const float4* rb = recS + (size_t)b * Fn * 3;
    const unsigned long long* btp = bins + ((size_t)b * 256 + tile) * NWORD;

    // expand tile bitmask -> LDS face list
    if (tid < NWORD) smCnt[tid] = (int)__popcll(btp[tid]);
    __syncthreads();
    if (tid < NWORD) {
        int off = 0;
        for (int j = 0; j < tid; ++j) off += smCnt[j];
        unsigned long long m = btp[tid];
        int base = tid << 6;
        while (m) {
            int bit = __ffsll((unsigned long long)m) - 1;
            m &= m - 1;
            smList[off++] = (unsigned short)(base + bit);
        }
        if (tid == NWORD - 1) smL = off;   // last prefix end == total
    }
    __syncthreads();
    int L = smL;

    unsigned long long best = ~0ull;
    int chunk = slice * NSEG + seg;          // 0..63
    int lo = (chunk * L) >> 6;
    int hi = ((chunk + 1) * L) >> 6;
    for (int j = lo; j < hi; ++j) {
        int f = smList[j];
        const float4* pr = rb + (size_t)f * 3;
        float4 q0 = pr[0];
        float4 q1 = pr[1];
        float x0 = q0.x, y0 = q0.y, x1 = q0.z, y1 = q0.w;
        float x2 = q1.x, y2 = q1.y, as = q1.w;
        // exact reference op order (_edge), contraction off
        float w0 = (px - x1) * (y2 - y1) - (py - y1) * (x2 - x1);
        float w1 = (px - x2) * (y0 - y2) - (py - y2) * (x0 - x2);
        float w2 = (px - x0) * (y1 - y0) - (py - y0) * (x1 - x0);
        bool ins = (as > 0.0f) ? (w0 >= 0.0f && w1 >= 0.0f && w2 >= 0.0f)
                               : (w0 <= 0.0f && w1 <= 0.0f && w2 <= 0.0f);
        // (binned faces all have |area| > EPS_AREA, so areaok is implied)
        if (ins) {
            float b0 = w0 / as;
            float b1 = w1 / as;
            float b2 = w2 / as;
            float4 q2 = pr[2];
            float zp = (b0 * q2.x + b1 * q2.y) + b2 * q2.z;
            if (zp > EPS_Z_F) {
                unsigned long long ck =
                    ((unsigned long long)__float_as_uint(zp) << 32) | (unsigned)f;
                if (ck < best) best = ck;   // min z, then min idx = argmin-first
            }
        }
    }
    smK[seg * 64 + lane] = best;
    __syncthreads();

    if (tid < 64) {
        unsigned long long bk = smK[tid];
        #pragma unroll
        for (int s = 1; s < NSEG; ++s) {
            unsigned long long k = smK[s * 64 + tid];
            if (k < bk) bk = k;
        }
        if (bk != ~0ull) {
            int p = b * (Hn * Wn) + h * Wn + w;
            atomicMin(&keybuf[p], bk);   // device-scope, commutative => deterministic
        }
    }
}

__global__ __launch_bounds__(256)
void writer_kernel(const float4* __restrict__ recS,
                   const unsigned long long* __restrict__ keybuf,
                   float* __restrict__ out) {
    int p = blockIdx.x * blockDim.x + threadIdx.x;
    if (p >= Bn * Hn * Wn) return;
    int b = p >> 14;
    int hw = p & 16383;
    int h = hw >> 7;
    int w = hw & 127;
    float px = 1.0f - (2.0f * ((float)w + 0.5f)) / (float)Wn;
    float py = 1.0f - (2.0f * ((float)h + 0.5f)) / (float)Hn;
    const float4* rb = recS + (size_t)b * Fn * 3;
    unsigned long long bk = keybuf[p];
    const int HWB = Bn * Hn * Wn;
    float o_idx = -1.0f, o_z = -1.0f, ob0 = -1.0f, ob1 = -1.0f, ob2 = -1.0f, o_d = -1.0f;
    if (bk != ~0ull) {
        int f = (int)(bk & 0xFFFFFFFFu);
        float4 q0 = rb[(size_t)f * 3 + 0];
        float4 q1 = rb[(size_t)f * 3 + 1];
        float x0 = q0.x, y0 = q0.y, x1 = q0.z, y1 = q0.w;
        float x2 = q1.x, y2 = q1.y, as = q1.w;
        // winner bary: exactly the reference phase-2 expressions
        float w0 = (px - x1) * (y2 - y1) - (py - y1) * (x2 - x1);
        float w1 = (px - x2) * (y0 - y2) - (py - y2) * (x0 - x2);
        float w2 = (px - x0) * (y1 - y0) - (py - y0) * (x1 - x0);
        float c0 = w0 / as, c1 = w1 / as, c2 = w2 / as;
        auto segd = [&](float ax, float ay, float bx, float by) -> float {
            float dx = bx - ax, dy = by - ay;
            float l2 = dx * dx + dy * dy;
            l2 = (l2 > 1e-12f) ? l2 : 1e-12f;
            float q = ((px - ax) * dx + (py - ay) * dy) / l2;
            q = (q < 0.0f) ? 0.0f : ((q > 1.0f) ? 1.0f : q);
            float ex = (ax + q * dx) - px;
            float ey = (ay + q * dy) - py;
            return ex * ex + ey * ey;
        };
        float d2 = fminf(fminf(segd(x0, y0, x1, y1), segd(x1, y1, x2, y2)),
                         segd(x2, y2, x0, y0));
        bool inside_b = (c0 >= 0.0f) && (c1 >= 0.0f) && (c2 >= 0.0f);
        o_idx = (float)f;
        o_z = __uint_as_float((unsigned)(bk >> 32));
        ob0 = c0; ob1 = c1; ob2 = c2;
        o_d = inside_b ? -d2 : d2;
    }
    out[p] = o_idx;
    out[HWB + p] = o_z;
    out[2 * HWB + p * 3 + 0] = ob0;
    out[2 * HWB + p * 3 + 1] = ob1;
    out[2 * HWB + p * 3 + 2] = ob2;
    out[5 * HWB + p] = o_d;
}

extern "C" void kernel_launch(void* const* d_in, const int* in_sizes, int n_in,
                              void* d_out, int out_size, void* d_ws, size_t ws_size,
                              hipStream_t stream) {
    const float* verts = (const float*)d_in[0];
    const float* R     = (const float*)d_in[1];
    const float* T     = (const float*)d_in[2];
    const float* focal = (const float*)d_in[3];
    const int*   faces = (const int*)d_in[4];
    float* out = (float*)d_out;
    char* ws = (char*)d_ws;
    float4* recS               = (float4*)(ws);
    unsigned* bboxT            = (unsigned*)(ws + 144000);
    unsigned long long* bins   = (unsigned long long*)(ws + 156000);
    unsigned long long* keybuf = (unsigned long long*)(ws + 254304);

    int nzero = Bn * 256 * NWORD + Bn * Hn * Wn;   // 45056
    hipLaunchKernelGGL(zero_kernel, dim3((nzero + 255) / 256), dim3(256), 0, stream,
                       bins, keybuf);
    hipLaunchKernelGGL(proj_kernel, dim3((Bn * Fn + 255) / 256), dim3(256), 0, stream,
                       verts, R, T, focal, faces, recS, bboxT);
    hipLaunchKernelGGL(bin_kernel, dim3((Bn * Fn * 16 + 255) / 256), dim3(256), 0, stream,
                       bboxT, bins);
    hipLaunchKernelGGL(raster_kernel, dim3(Bn * 256 * NSLICE), dim3(TPB), 0, stream,
                       recS, bins, keybuf);
    hipLaunchKernelGGL(writer_kernel, dim3((Bn * Hn * Wn + 255) / 256), dim3(256),
                       0, stream, recS, keybuf, out);
}

// Round 7
// 98.407 us; speedup vs baseline: 1.6543x; 1.0442x over previous
//
#include <hip/hip_runtime.h>
#include <math.h>

#pragma clang fp contract(off)

#define Bn 2
#define Vn 8000
#define Fn 1500
#define Hn 128
#define Wn 128
#define EPS_AREA_F 1e-8f
#define EPS_Z_F 1e-4f
#define NSEG 8              // waves per raster block
#define NSLICE 8            // raster blocks per tile
#define TPB (NSEG * 64)     // 512

// ws layout:
//   recS    : float4[Bn*Fn*3]          @ 0        (144000 B)
//   bboxT   : u32[Bn*Fn]               @ 144000   (12000 B)
//   keyslice: u64[Bn*16384*NSLICE]     @ 156000   (2 MB) — written unconditionally,
//                                                  no init, no atomics, deterministic.

__global__ void proj_kernel(const float* __restrict__ verts, const float* __restrict__ R,
                            const float* __restrict__ T, const float* __restrict__ focal,
                            const int* __restrict__ faces,
                            float4* __restrict__ recS, unsigned* __restrict__ bboxT) {
    int t = blockIdx.x * blockDim.x + threadIdx.x;
    if (t >= Bn * Fn) return;
    int b = t / Fn;
    int f = t - b * Fn;
    const float* Rb = R + b * 9;
    const float* Tb = T + b * 3;
    float fo = focal[0];
    float X[3], Y[3], Z[3];
    for (int k = 0; k < 3; ++k) {
        int vi = faces[f * 3 + k];
        const float* v = verts + ((size_t)b * Vn + vi) * 3;
        float v0 = v[0], v1 = v[1], v2 = v[2];
        float vx = v0 * Rb[0] + v1 * Rb[3] + v2 * Rb[6] + Tb[0];
        float vy = v0 * Rb[1] + v1 * Rb[4] + v2 * Rb[7] + Tb[1];
        float vz = v0 * Rb[2] + v1 * Rb[5] + v2 * Rb[8] + Tb[2];
        X[k] = (fo * vx) / vz;
        Y[k] = (fo * vy) / vz;
        Z[k] = vz;
    }
    float area = (X[2] - X[0]) * (Y[1] - Y[0]) - (Y[2] - Y[0]) * (X[1] - X[0]);
    float as = (fabsf(area) > EPS_AREA_F) ? area : EPS_AREA_F;
    recS[t * 3 + 0] = make_float4(X[0], Y[0], X[1], Y[1]);
    recS[t * 3 + 1] = make_float4(X[2], Y[2], area, as);
    recS[t * 3 + 2] = make_float4(Z[0], Z[1], Z[2], 0.0f);

    unsigned pk = 0xFFFFFFFFu;   // sentinel: face can never be 'inside' -> exact skip
    if (fabsf(area) > EPS_AREA_F) {
        float xmin = fminf(X[0], fminf(X[1], X[2]));
        float xmax = fmaxf(X[0], fmaxf(X[1], X[2]));
        float ymin = fminf(Y[0], fminf(Y[1], Y[2]));
        float ymax = fmaxf(Y[0], fmaxf(Y[1], Y[2]));
        const float D = 0.02f;   // pad >> max fp sign-flip dilation (~1e-5 NDC)
        float wlo = ceilf(64.0f * (1.0f - xmax - D) - 0.5f);
        float whi = floorf(64.0f * (1.0f - xmin + D) - 0.5f);
        float hlo = ceilf(64.0f * (1.0f - ymax - D) - 0.5f);
        float hhi = floorf(64.0f * (1.0f - ymin + D) - 0.5f);
        wlo = fmaxf(wlo, 0.0f); whi = fminf(whi, 127.0f);
        hlo = fmaxf(hlo, 0.0f); hhi = fminf(hhi, 127.0f);
        // NaN-safe: NaN comparisons fail -> skip; +-inf clamps to full screen.
        if ((wlo <= whi) && (hlo <= hhi)) {
            int tx0 = (int)wlo >> 3, tx1 = (int)whi >> 3;
            int ty0 = (int)hlo >> 3, ty1 = (int)hhi >> 3;
            pk = (unsigned)tx0 | ((unsigned)tx1 << 8) |
                 ((unsigned)ty0 << 16) | ((unsigned)ty1 << 24);
        }
    }
    bboxT[t] = pk;
}

__global__ __launch_bounds__(TPB)
void raster_kernel(const float4* __restrict__ recS, const unsigned* __restrict__ bboxT,
                   unsigned long long* __restrict__ keyslice) {
    __shared__ unsigned long long smK[NSEG * 64];    // 4096 B

    int tid = threadIdx.x;
    int lane = tid & 63;
    int seg = tid >> 6;
    int blk = blockIdx.x;                 // ((b*256 + tile)*NSLICE + slice)
    int slice = blk & (NSLICE - 1);
    int bt_ = blk >> 3;
    int b = bt_ >> 8;
    int tile = bt_ & 255;
    int ty = tile >> 4, tx = tile & 15;
    int h = (ty << 3) | (lane >> 3);
    int w = (tx << 3) | (lane & 7);
    float px = 1.0f - (2.0f * ((float)w + 0.5f)) / (float)Wn;
    float py = 1.0f - (2.0f * ((float)h + 0.5f)) / (float)Hn;

    // Deterministic partition: chunk c owns face-index range [(c*Fn)>>6, ((c+1)*Fn)>>6).
    // No shared list, no atomics — identical coverage in every block by construction.
    int chunk = slice * NSEG + seg;          // 0..63
    int lo = (chunk * Fn) >> 6;
    int hi = ((chunk + 1) * Fn) >> 6;

    const unsigned* bbb = bboxT + (size_t)b * Fn;
    const float4* rb = recS + (size_t)b * Fn * 3;
    unsigned long long best = ~0ull;

    for (int f = lo; f < hi; ++f) {
        unsigned pk = bbb[f];                 // wave-uniform load -> uniform branch
        if (pk == 0xFFFFFFFFu) continue;
        int tx0 = pk & 0xFF, tx1 = (pk >> 8) & 0xFF;
        int ty0 = (pk >> 16) & 0xFF, ty1 = (pk >> 24) & 0xFF;
        if (tx < tx0 || tx > tx1 || ty < ty0 || ty > ty1) continue;
        const float4* pr = rb + (size_t)f * 3;
        float4 q0 = pr[0];
        float4 q1 = pr[1];
        float x0 = q0.x, y0 = q0.y, x1 = q0.z, y1 = q0.w;
        float x2 = q1.x, y2 = q1.y, as = q1.w;
        // exact reference op order (_edge), contraction off
        float w0 = (px - x1) * (y2 - y1) - (py - y1) * (x2 - x1);
        float w1 = (px - x2) * (y0 - y2) - (py - y2) * (x0 - x2);
        float w2 = (px - x0) * (y1 - y0) - (py - y0) * (x1 - x0);
        bool ins = (as > 0.0f) ? (w0 >= 0.0f && w1 >= 0.0f && w2 >= 0.0f)
                               : (w0 <= 0.0f && w1 <= 0.0f && w2 <= 0.0f);
        // (bbox-passing faces all have |area| > EPS_AREA, so areaok is implied)
        if (ins) {
            float b0 = w0 / as;
            float b1 = w1 / as;
            float b2 = w2 / as;
            float4 q2 = pr[2];
            float zp = (b0 * q2.x + b1 * q2.y) + b2 * q2.z;
            if (zp > EPS_Z_F) {
                unsigned long long ck =
                    ((unsigned long long)__float_as_uint(zp) << 32) | (unsigned)f;
                if (ck < best) best = ck;   // min z, then min idx = argmin-first
            }
        }
    }
    smK[seg * 64 + lane] = best;
    __syncthreads();

    if (tid < 64) {
        unsigned long long bk = smK[tid];
        #pragma unroll
        for (int s = 1; s < NSEG; ++s) {
            unsigned long long k = smK[s * 64 + tid];
            if (k < bk) bk = k;
        }
        int hh = (ty << 3) | (tid >> 3);
        int ww = (tx << 3) | (tid & 7);
        int p = (b << 14) + hh * Wn + ww;
        keyslice[(size_t)p * NSLICE + slice] = bk;   // unconditional: no init needed
    }
}

__global__ __launch_bounds__(256)
void writer_kernel(const float4* __restrict__ recS,
                   const unsigned long long* __restrict__ keyslice,
                   float* __restrict__ out) {
    int p = blockIdx.x * blockDim.x + threadIdx.x;
    if (p >= Bn * Hn * Wn) return;
    int b = p >> 14;
    int hw = p & 16383;
    int h = hw >> 7;
    int w = hw & 127;
    float px = 1.0f - (2.0f * ((float)w + 0.5f)) / (float)Wn;
    float py = 1.0f - (2.0f * ((float)h + 0.5f)) / (float)Hn;
    const unsigned long long* ks = keyslice + (size_t)p * NSLICE;
    unsigned long long bk = ks[0];
    #pragma unroll
    for (int s = 1; s < NSLICE; ++s) {
        unsigned long long k = ks[s];
        if (k < bk) bk = k;
    }
    const float4* rb = recS + (size_t)b * Fn * 3;
    const int HWB = Bn * Hn * Wn;
    float o_idx = -1.0f, o_z = -1.0f, ob0 = -1.0f, ob1 = -1.0f, ob2 = -1.0f, o_d = -1.0f;
    if (bk != ~0ull) {
        int f = (int)(bk & 0xFFFFFFFFu);
        float4 q0 = rb[(size_t)f * 3 + 0];
        float4 q1 = rb[(size_t)f * 3 + 1];
        float x0 = q0.x, y0 = q0.y, x1 = q0.z, y1 = q0.w;
        float x2 = q1.x, y2 = q1.y, as = q1.w;
        // winner bary: exactly the reference phase-2 expressions
        float w0 = (px - x1) * (y2 - y1) - (py - y1) * (x2 - x1);
        float w1 = (px - x2) * (y0 - y2) - (py - y2) * (x0 - x2);
        float w2 = (px - x0) * (y1 - y0) - (py - y0) * (x1 - x0);
        float c0 = w0 / as, c1 = w1 / as, c2 = w2 / as;
        auto segd = [&](float ax, float ay, float bx, float by) -> float {
            float dx = bx - ax, dy = by - ay;
            float l2 = dx * dx + dy * dy;
            l2 = (l2 > 1e-12f) ? l2 : 1e-12f;
            float q = ((px - ax) * dx + (py - ay) * dy) / l2;
            q = (q < 0.0f) ? 0.0f : ((q > 1.0f) ? 1.0f : q);
            float ex = (ax + q * dx) - px;
            float ey = (ay + q * dy) - py;
            return ex * ex + ey * ey;
        };
        float d2 = fminf(fminf(segd(x0, y0, x1, y1), segd(x1, y1, x2, y2)),
                         segd(x2, y2, x0, y0));
        bool inside_b = (c0 >= 0.0f) && (c1 >= 0.0f) && (c2 >= 0.0f);
        o_idx = (float)f;
        o_z = __uint_as_float((unsigned)(bk >> 32));
        ob0 = c0; ob1 = c1; ob2 = c2;
        o_d = inside_b ? -d2 : d2;
    }
    out[p] = o_idx;
    out[HWB + p] = o_z;
    out[2 * HWB + p * 3 + 0] = ob0;
    out[2 * HWB + p * 3 + 1] = ob1;
    out[2 * HWB + p * 3 + 2] = ob2;
    out[5 * HWB + p] = o_d;
}

extern "C" void kernel_launch(void* const* d_in, const int* in_sizes, int n_in,
                              void* d_out, int out_size, void* d_ws, size_t ws_size,
                              hipStream_t stream) {
    const float* verts = (const float*)d_in[0];
    const float* R     = (const float*)d_in[1];
    const float* T     = (const float*)d_in[2];
    const float* focal = (const float*)d_in[3];
    const int*   faces = (const int*)d_in[4];
    float* out = (float*)d_out;
    char* ws = (char*)d_ws;
    float4* recS                 = (float4*)(ws);
    unsigned* bboxT              = (unsigned*)(ws + 144000);
    unsigned long long* keyslice = (unsigned long long*)(ws + 156000);

    hipLaunchKernelGGL(proj_kernel, dim3((Bn * Fn + 255) / 256), dim3(256), 0, stream,
                       verts, R, T, focal, faces, recS, bboxT);
    hipLaunchKernelGGL(raster_kernel, dim3(Bn * 256 * NSLICE), dim3(TPB), 0, stream,
                       recS, bboxT, keyslice);
    hipLaunchKernelGGL(writer_kernel, dim3((Bn * Hn * Wn + 255) / 256), dim3(256),
                       0, stream, recS, keyslice, out);
}